// Round 4
// baseline (237.581 us; speedup 1.0000x reference)
//
#include <hip/hip_runtime.h>
#include <math.h>

#define EPS 1e-5f
#define TPB 512            // 8 waves; 4 float4-granules per thread (T=8192)
#define NJ  4              // granules per thread

typedef float f32x4 __attribute__((ext_vector_type(4)));  // clang vector: ok for nontemporal builtins

// One block per (b,c) row. Thread t owns granules g = j*TPB + t (j=0..3),
// i.e. exactly the coalesced float4 positions -- data never leaves registers.
// Causal prefix at granule granularity: granule order is j-major then t, so
// per-j block scans (wave shuffle-scan + cross-wave combine) + running j
// totals give each granule its exclusive (sum, sumsq) prefix. Replay of the
// 4 elements inside each granule is sequential per granule, independent
// across granules (good ILP). Output stored nontemporally to keep x in LLC.
__global__ __launch_bounds__(TPB, 6) void causal_ln_kernel(
    const float* __restrict__ x,
    const float* __restrict__ weight,
    const float* __restrict__ bias,
    float* __restrict__ out,
    int C, int T)
{
    __shared__ float wt [NJ][8];   // [j][wave] inclusive wave totals (sum)
    __shared__ float wt2[NJ][8];   // [j][wave] (sumsq)

    const int row  = blockIdx.x;
    const int c    = row % C;
    const float wv = weight[c];
    const float bv = bias[c];
    const long long base = (long long)row * (long long)T;

    const int t    = threadIdx.x;   // 0..511
    const int lane = t & 63;
    const int wid  = t >> 6;        // 0..7

    // ---- coalesced load: granule j*TPB + t ----
    const f32x4* xg = (const f32x4*)(x + base);
    f32x4 v[NJ];
#pragma unroll
    for (int j = 0; j < NJ; ++j) v[j] = xg[j * TPB + t];

    // ---- per-granule sums ----
    float s[NJ], s2[NJ];
#pragma unroll
    for (int j = 0; j < NJ; ++j) {
        s [j] = v[j].x + v[j].y + v[j].z + v[j].w;
        s2[j] = v[j].x * v[j].x + v[j].y * v[j].y
              + v[j].z * v[j].z + v[j].w * v[j].w;
    }

    // ---- per-j wave64 inclusive shuffle scans ----
    float ws[NJ], ws2[NJ];
#pragma unroll
    for (int j = 0; j < NJ; ++j) { ws[j] = s[j]; ws2[j] = s2[j]; }
#pragma unroll
    for (int off = 1; off < 64; off <<= 1) {
#pragma unroll
        for (int j = 0; j < NJ; ++j) {
            float a  = __shfl_up(ws [j], off, 64);
            float a2 = __shfl_up(ws2[j], off, 64);
            ws [j] += (lane >= off) ? a  : 0.f;
            ws2[j] += (lane >= off) ? a2 : 0.f;
        }
    }

    // ---- cross-wave totals (one barrier total) ----
    if (lane == 63) {
#pragma unroll
        for (int j = 0; j < NJ; ++j) { wt[j][wid] = ws[j]; wt2[j][wid] = ws2[j]; }
    }
    __syncthreads();

    // ---- per-granule exclusive prefix = j-prefix + wave-prefix + lane-excl ----
    float start[NJ], start2[NJ];
    {
        float jpre = 0.f, jpre2 = 0.f;
#pragma unroll
        for (int j = 0; j < NJ; ++j) {
            float wpre = 0.f, wpre2 = 0.f, btot = 0.f, btot2 = 0.f;
#pragma unroll
            for (int w = 0; w < 8; ++w) {
                float a = wt[j][w], a2 = wt2[j][w];     // broadcast reads
                btot  += a;  btot2 += a2;
                wpre  += (w < wid) ? a  : 0.f;
                wpre2 += (w < wid) ? a2 : 0.f;
            }
            start [j] = jpre  + wpre  + (ws [j] - s [j]);   // excl = incl - self
            start2[j] = jpre2 + wpre2 + (ws2[j] - s2[j]);
            jpre  += btot;  jpre2 += btot2;
        }
    }

    // ---- replay: causal mean/var + normalize, per granule ----
#pragma unroll
    for (int j = 0; j < NJ; ++j) {
        float run  = start [j];
        float run2 = start2[j];
        float cnt  = (float)(j * (TPB * 4) + t * 4);   // elements before granule
        float xs[4] = {v[j].x, v[j].y, v[j].z, v[j].w};
#pragma unroll
        for (int i = 0; i < 4; ++i) {
            float xi = xs[i];
            run  += xi;
            run2 += xi * xi;
            cnt  += 1.f;
            float rc   = __builtin_amdgcn_rcpf(cnt);
            float mean = run * rc;
            float var  = run2 * rc - mean * mean;
            var = fmaxf(var, 0.f);
            float rinv = __builtin_amdgcn_rsqf(var + EPS);
            xs[i] = (xi - mean) * rinv * wv + bv;
        }
        f32x4 r = {xs[0], xs[1], xs[2], xs[3]};
        v[j] = r;
    }

    // ---- coalesced nontemporal store ----
    f32x4* og = (f32x4*)(out + base);
#pragma unroll
    for (int j = 0; j < NJ; ++j)
        __builtin_nontemporal_store(v[j], &og[j * TPB + t]);
}

extern "C" void kernel_launch(void* const* d_in, const int* in_sizes, int n_in,
                              void* d_out, int out_size, void* d_ws, size_t ws_size,
                              hipStream_t stream) {
    const float* x      = (const float*)d_in[0];
    const float* weight = (const float*)d_in[1];
    const float* bias   = (const float*)d_in[2];
    float* out          = (float*)d_out;

    const int C = in_sizes[1];            // 512
    const int T = 8192;
    const int rows = in_sizes[0] / T;     // 4096

    dim3 grid(rows), block(TPB);
    hipLaunchKernelGGL(causal_ln_kernel, grid, block, 0, stream,
                       x, weight, bias, out, C, T);
}